// Round 4
// baseline (639.173 us; speedup 1.0000x reference)
//
#include <hip/hip_runtime.h>

typedef __attribute__((ext_vector_type(4))) _Float16 f16x4;
typedef __attribute__((ext_vector_type(4))) float f32x4;

#define NB 4096
#define TT 200
#define DD 64
#define H0 128
#define H1 64

// Transposed-GEMM DIN attention, plain-fp16 weights/activations (fp32 accum,
// bias, softmax, pooling). Per block b:
//   M_b = W0b - W0c + diag(q) W0d   (64x128 fp16, XOR-swizzled in LDS as [h][d])
//   cb  = b0 + q@(W0a + W0c)        (fp32 LDS)
//   layer0^T: h0t = M_b^T @ k^T  -> D-frag == layer1 B-frag (chained in regs)
//   layer1^T: h1t = W1^T @ h0t; logit = h1 . Wf; masked online softmax; pool v.
// LDS 34.1 KB -> 4 blocks/CU; target <=128 VGPRs for 4 waves/SIMD (50% occ).
__global__ __launch_bounds__(256, 4)
void din_attn(const float* __restrict__ q, const float* __restrict__ k,
              const float* __restrict__ v, const int* __restrict__ mask,
              const float* __restrict__ W0, const float* __restrict__ b0,
              const float* __restrict__ W1, const float* __restrict__ b1,
              const float* __restrict__ Wf, float* __restrict__ out)
{
  const int b    = blockIdx.x;
  const int tid  = threadIdx.x;
  const int lane = tid & 63;
  const int wid  = tid >> 6;
  const int r16  = lane & 15;   // t-col within strip / A-row select
  const int g4   = lane >> 4;   // k-subgroup / D row-subgroup

  // XOR-swizzled: element (row,c) at [row*PITCH + (c ^ ((row&7)<<3))]
  __shared__ __align__(16) _Float16 MhT[H0 * 64];   // 16 KB
  __shared__ __align__(16) _Float16 W1T[H1 * 128];  // 16 KB
  __shared__ float cbS[H0];
  __shared__ float b1S[H1];
  __shared__ float WfS[H1];
  __shared__ float scratch[280];  // cb partials -> reuse: owav[4][68]+msh[4]+ssh[4]

  const float* qb = q + b * DD;
  const float* kb = k + (size_t)b * TT * DD;
  const float* vb = v + (size_t)b * TT * DD;
  const int*   mb = mask + b * TT;

  // ---- prologue ----
  {
    int h = tid & 127, half = tid >> 7;
    float s = 0.f;
    #pragma unroll 8
    for (int i = 0; i < 32; ++i) {
      int d = half * 32 + i;
      s += qb[d] * (W0[d * H0 + h] + W0[(128 + d) * H0 + h]);
    }
    scratch[tid] = s;
  }
  // M_b^T -> LDS (fp16, [h][d], swizzled)
  #pragma unroll 4
  for (int i = 0; i < 32; ++i) {
    int idx = i * 256 + tid;
    int h = idx & 127, d = idx >> 7;
    float val = W0[(64 + d) * H0 + h] - W0[(128 + d) * H0 + h]
              + qb[d] * W0[(192 + d) * H0 + h];
    MhT[h * 64 + (d ^ ((h & 7) << 3))] = (_Float16)val;
  }
  // W1^T -> LDS (fp16, [j][h], swizzled)
  #pragma unroll 4
  for (int i = 0; i < 32; ++i) {
    int idx = i * 256 + tid;
    int hh = idx >> 6, j = idx & 63;
    W1T[j * 128 + (hh ^ ((j & 7) << 3))] = (_Float16)W1[idx];
  }
  if (tid < H1) { b1S[tid] = b1[tid]; WfS[tid] = Wf[tid]; }
  __syncthreads();
  if (tid < H0) cbS[tid] = scratch[tid] + scratch[tid + 128] + b0[tid];

  // first strip's k loads issued before the barrier (independent of LDS)
  float4 kq[4];
  {
    const int trow = wid * 16 + r16;   // always < 200
    #pragma unroll
    for (int ks = 0; ks < 4; ++ks)
      kq[ks] = *(const float4*)(kb + trow * DD + ks * 16 + 4 * g4);
  }
  __syncthreads();

  float m_run = -1e30f, s_run = 0.f, o_run = 0.f;

  for (int s = wid; s < 13; s += 4) {
    const int t0   = s * 16;
    const int trow = t0 + r16;
    const bool tv  = trow < TT;

    int mm = tv ? mb[trow] : -1;

    // v stream for this strip (used only at the end -> latency self-hidden)
    float vv[16];
    #pragma unroll
    for (int i = 0; i < 16; ++i) {
      int t = t0 + i;
      vv[i] = (t < TT) ? vb[t * DD + lane] : 0.f;
    }

    // convert current k to fp16 B-fragments, then prefetch next strip's k
    f16x4 bh[4];
    #pragma unroll
    for (int ks = 0; ks < 4; ++ks) {
      float kf[4] = {kq[ks].x, kq[ks].y, kq[ks].z, kq[ks].w};
      #pragma unroll
      for (int j = 0; j < 4; ++j) bh[ks][j] = (_Float16)kf[j];
    }
    const int sn = s + 4;
    if (sn < 13) {
      const int trn = sn * 16 + r16;
      const bool tvn = trn < TT;
      #pragma unroll
      for (int ks = 0; ks < 4; ++ks) {
        float4 z = {0.f, 0.f, 0.f, 0.f};
        kq[ks] = tvn ? *(const float4*)(kb + trn * DD + ks * 16 + 4 * g4) : z;
      }
    }

    // ---- layer0^T: h0t[h=c*16+4g4+r][t0+r16] ----
    f16x4 hh[8];
    #pragma unroll
    for (int c = 0; c < 8; ++c) {
      const int row = c * 16 + r16;
      const _Float16* mbase = &MhT[row * 64];
      const int sw = (row & 7) << 3;
      f32x4 acc = {0.f, 0.f, 0.f, 0.f};
      #pragma unroll
      for (int ks = 0; ks < 4; ++ks) {
        f16x4 af = *(const f16x4*)(mbase + ((ks * 16 + 4 * g4) ^ sw));
        acc = __builtin_amdgcn_mfma_f32_16x16x16f16(af, bh[ks], acc, 0, 0, 0);
      }
      f32x4 cb4 = *(const f32x4*)(&cbS[c * 16 + 4 * g4]);
      #pragma unroll
      for (int r = 0; r < 4; ++r) {
        float hv = acc[r] + cb4[r];
        hh[c][r] = (_Float16)(hv > 0.f ? hv : 0.f);
      }
    }

    // ---- layer1^T + logit ----
    float p = 0.f;
    #pragma unroll
    for (int c1 = 0; c1 < 4; ++c1) {
      const int row = c1 * 16 + r16;
      const _Float16* wbase = &W1T[row * 128];
      const int sw = (row & 7) << 3;
      f32x4 acc = {0.f, 0.f, 0.f, 0.f};
      #pragma unroll
      for (int ks = 0; ks < 8; ++ks) {
        f16x4 af = *(const f16x4*)(wbase + ((ks * 16 + 4 * g4) ^ sw));
        acc = __builtin_amdgcn_mfma_f32_16x16x16f16(af, hh[ks], acc, 0, 0, 0);
      }
      f32x4 b14 = *(const f32x4*)(&b1S[c1 * 16 + 4 * g4]);
      f32x4 wf4 = *(const f32x4*)(&WfS[c1 * 16 + 4 * g4]);
      #pragma unroll
      for (int r = 0; r < 4; ++r) {
        float h1 = acc[r] + b14[r];
        h1 = h1 > 0.f ? h1 : 0.f;
        p = fmaf(h1, wf4[r], p);
      }
    }

    // reduce logit over the 4 g4 replicas (same t-col)
    p += __shfl_xor(p, 16, 64);
    p += __shfl_xor(p, 32, 64);
    // mask: keep / masked(-1e30) / pad(-2e30)
    p = (mm == 1) ? p : (mm == 0 ? -1e30f : -2e30f);

    // online softmax + v pooling, no lt/e arrays (readlane broadcasts)
    float m_new = m_run;
    #pragma unroll
    for (int i = 0; i < 16; ++i) m_new = fmaxf(m_new, __shfl(p, i, 64));
    float scale = __expf(m_run - m_new);
    s_run *= scale;
    o_run *= scale;
    #pragma unroll
    for (int i = 0; i < 16; ++i) {
      float e = __expf(__shfl(p, i, 64) - m_new);
      s_run += e;
      o_run = fmaf(e, vv[i], o_run);
    }
    m_run = m_new;
  }

  // ---- cross-wave flash combine (scratch: owav[4][68] @0, msh @272, ssh @276) ----
  scratch[wid * 68 + lane] = o_run;
  if (lane == 0) { scratch[272 + wid] = m_run; scratch[276 + wid] = s_run; }
  __syncthreads();

  if (tid < DD) {
    float mstar = fmaxf(fmaxf(scratch[272], scratch[273]),
                        fmaxf(scratch[274], scratch[275]));
    float acc = 0.f, ssum = 0.f;
    #pragma unroll
    for (int w = 0; w < 4; ++w) {
      float f = __expf(scratch[272 + w] - mstar);
      acc  += scratch[w * 68 + tid] * f;
      ssum += scratch[276 + w] * f;
    }
    out[b * DD + tid] = acc / ssum;
  }
}

extern "C" void kernel_launch(void* const* d_in, const int* in_sizes, int n_in,
                              void* d_out, int out_size, void* d_ws, size_t ws_size,
                              hipStream_t stream) {
  const float* q    = (const float*)d_in[0];
  const float* k    = (const float*)d_in[1];
  const float* v    = (const float*)d_in[2];
  const int*   mask = (const int*)d_in[3];
  const float* W0   = (const float*)d_in[4];
  const float* b0   = (const float*)d_in[5];
  const float* W1   = (const float*)d_in[6];
  const float* b1   = (const float*)d_in[7];
  const float* Wf   = (const float*)d_in[8];
  float* out = (float*)d_out;
  din_attn<<<dim3(NB), dim3(256), 0, stream>>>(q, k, v, mask, W0, b0, W1, b1, Wf, out);
}

// Round 5
// 506.697 us; speedup vs baseline: 1.2615x; 1.2615x over previous
//
#include <hip/hip_runtime.h>

typedef __attribute__((ext_vector_type(4))) _Float16 f16x4;
typedef __attribute__((ext_vector_type(4))) float f32x4;

#define NB 4096
#define TT 200
#define DD 64
#define H0 128
#define H1 64

// Transposed-GEMM DIN attention, fp16 weights/activations, fp32 accum/softmax.
//   M_b = W0b - W0c + diag(q) W0d   (64x128 fp16, XOR-swizzled LDS [h][d])
//   layer0^T: h0t = M_b^T @ k^T  -> D-frag == layer1 B-frag (register chain)
//   layer1^T: h1t = W1^T @ h0t; logit -> LDS.
// Then exact two-pass softmax over LDS logits, then v-streaming pooling pass.
// Deferred softmax/pooling cuts the strip-loop register set (~-20 VGPRs) so
// 3 waves/SIMD fit at launch_bounds(256,3); (256,4) forces a 64/64 arch/acc
// split that spills ~1.5 GB (R2/R4 evidence).
__global__ __launch_bounds__(256, 3)
void din_attn(const float* __restrict__ q, const float* __restrict__ k,
              const float* __restrict__ v, const int* __restrict__ mask,
              const float* __restrict__ W0, const float* __restrict__ b0,
              const float* __restrict__ W1, const float* __restrict__ b1,
              const float* __restrict__ Wf, float* __restrict__ out)
{
  const int b    = blockIdx.x;
  const int tid  = threadIdx.x;
  const int lane = tid & 63;
  const int wid  = tid >> 6;
  const int r16  = lane & 15;   // t-col within strip / A-row select
  const int g4   = lane >> 4;   // k-subgroup / D row-subgroup

  // XOR-swizzled: element (row,c) at [row*PITCH + (c ^ ((row&7)<<3))]
  __shared__ __align__(16) _Float16 MhT[H0 * 64];   // 16 KB
  __shared__ __align__(16) _Float16 W1T[H1 * 128];  // 16 KB
  __shared__ float cbS[H0];
  __shared__ float b1S[H1];
  __shared__ float WfS[H1];
  __shared__ float sP[208];       // logits
  __shared__ float sW[208];       // softmax weights
  __shared__ float red[8];        // cross-wave reduce (max, sum)
  __shared__ float scratch[256];  // cb partials -> reuse: pooling partials

  const float* qb = q + b * DD;
  const float* kb = k + (size_t)b * TT * DD;
  const float* vb = v + (size_t)b * TT * DD;
  const int*   mb = mask + b * TT;

  // ---- prologue ----
  {
    int h = tid & 127, half = tid >> 7;
    float s = 0.f;
    #pragma unroll 8
    for (int i = 0; i < 32; ++i) {
      int d = half * 32 + i;
      s += qb[d] * (W0[d * H0 + h] + W0[(128 + d) * H0 + h]);
    }
    scratch[tid] = s;
  }
  // M_b^T -> LDS (fp16, [h][d], swizzled)
  #pragma unroll 4
  for (int i = 0; i < 32; ++i) {
    int idx = i * 256 + tid;
    int h = idx & 127, d = idx >> 7;
    float val = W0[(64 + d) * H0 + h] - W0[(128 + d) * H0 + h]
              + qb[d] * W0[(192 + d) * H0 + h];
    MhT[h * 64 + (d ^ ((h & 7) << 3))] = (_Float16)val;
  }
  // W1^T -> LDS (fp16, [j][h], swizzled)
  #pragma unroll 4
  for (int i = 0; i < 32; ++i) {
    int idx = i * 256 + tid;
    int hh = idx >> 6, j = idx & 63;
    W1T[j * 128 + (hh ^ ((j & 7) << 3))] = (_Float16)W1[idx];
  }
  if (tid < H1) { b1S[tid] = b1[tid]; WfS[tid] = Wf[tid]; }
  __syncthreads();
  if (tid < H0) cbS[tid] = scratch[tid] + scratch[tid + 128] + b0[tid];

  // first strip's k loads issued early (independent of LDS state)
  float4 kq[4];
  {
    const int trow = wid * 16 + r16;   // always < 200
    #pragma unroll
    for (int ks = 0; ks < 4; ++ks)
      kq[ks] = *(const float4*)(kb + trow * DD + ks * 16 + 4 * g4);
  }
  __syncthreads();

  // ---- pass 1: logits ----
  for (int s = wid; s < 13; s += 4) {
    const int t0   = s * 16;
    const int trow = t0 + r16;
    const bool tv  = trow < TT;
    int mm = tv ? mb[trow] : -1;

    // convert current k to fp16 B-fragments, then prefetch next strip's k
    f16x4 bh[4];
    #pragma unroll
    for (int ks = 0; ks < 4; ++ks) {
      float kf[4] = {kq[ks].x, kq[ks].y, kq[ks].z, kq[ks].w};
      #pragma unroll
      for (int j = 0; j < 4; ++j) bh[ks][j] = (_Float16)kf[j];
    }
    const int sn = s + 4;
    if (sn < 13) {
      const int trn = sn * 16 + r16;
      const bool tvn = trn < TT;
      #pragma unroll
      for (int ks = 0; ks < 4; ++ks) {
        float4 z = {0.f, 0.f, 0.f, 0.f};
        kq[ks] = tvn ? *(const float4*)(kb + trn * DD + ks * 16 + 4 * g4) : z;
      }
    }

    // layer0^T: h0t[h=c*16+4g4+r][t0+r16]
    f16x4 hh[8];
    #pragma unroll
    for (int c = 0; c < 8; ++c) {
      const int row = c * 16 + r16;
      const _Float16* mbase = &MhT[row * 64];
      const int sw = (row & 7) << 3;
      f32x4 acc = {0.f, 0.f, 0.f, 0.f};
      #pragma unroll
      for (int ks = 0; ks < 4; ++ks) {
        f16x4 af = *(const f16x4*)(mbase + ((ks * 16 + 4 * g4) ^ sw));
        acc = __builtin_amdgcn_mfma_f32_16x16x16f16(af, bh[ks], acc, 0, 0, 0);
      }
      f32x4 cb4 = *(const f32x4*)(&cbS[c * 16 + 4 * g4]);
      #pragma unroll
      for (int r = 0; r < 4; ++r) {
        float hv = acc[r] + cb4[r];
        hh[c][r] = (_Float16)(hv > 0.f ? hv : 0.f);
      }
    }

    // layer1^T + logit
    float p = 0.f;
    #pragma unroll
    for (int c1 = 0; c1 < 4; ++c1) {
      const int row = c1 * 16 + r16;
      const _Float16* wbase = &W1T[row * 128];
      const int sw = (row & 7) << 3;
      f32x4 acc = {0.f, 0.f, 0.f, 0.f};
      #pragma unroll
      for (int ks = 0; ks < 8; ++ks) {
        f16x4 af = *(const f16x4*)(wbase + ((ks * 16 + 4 * g4) ^ sw));
        acc = __builtin_amdgcn_mfma_f32_16x16x16f16(af, hh[ks], acc, 0, 0, 0);
      }
      f32x4 b14 = *(const f32x4*)(&b1S[c1 * 16 + 4 * g4]);
      f32x4 wf4 = *(const f32x4*)(&WfS[c1 * 16 + 4 * g4]);
      #pragma unroll
      for (int r = 0; r < 4; ++r) {
        float h1 = acc[r] + b14[r];
        h1 = h1 > 0.f ? h1 : 0.f;
        p = fmaf(h1, wf4[r], p);
      }
    }

    // reduce over the 4 g4 replicas; mask; store logit
    p += __shfl_xor(p, 16, 64);
    p += __shfl_xor(p, 32, 64);
    p = (mm == 1) ? p : (mm == 0 ? -1e30f : -2e30f);
    if (g4 == 0) sP[t0 + r16] = p;
  }
  __syncthreads();

  // ---- pass 2: exact softmax over sP[0..207] ----
  {
    float val = (tid < 208) ? sP[tid] : -3e30f;
    float m = val;
    #pragma unroll
    for (int off = 32; off >= 1; off >>= 1) m = fmaxf(m, __shfl_xor(m, off, 64));
    if (lane == 0) red[wid] = m;
    __syncthreads();
    float M = fmaxf(fmaxf(red[0], red[1]), fmaxf(red[2], red[3]));
    float e = (tid < 208) ? __expf(val - M) : 0.f;
    float se = e;
    #pragma unroll
    for (int off = 32; off >= 1; off >>= 1) se += __shfl_xor(se, off, 64);
    if (lane == 0) red[4 + wid] = se;
    __syncthreads();
    float S = (red[4] + red[5]) + (red[6] + red[7]);
    if (tid < 208) sW[tid] = e / S;
  }
  __syncthreads();

  // ---- pass 3: pooling, wave w covers t in [w*52, w*52+52) ----
  {
    float o0 = 0.f, o1 = 0.f, o2 = 0.f, o3 = 0.f;
    const int tbase = wid * 52;
    #pragma unroll 4
    for (int i = 0; i < 52; i += 4) {
      int t = tbase + i;
      if (t + 3 < TT) {
        o0 = fmaf(sW[t + 0], vb[(t + 0) * DD + lane], o0);
        o1 = fmaf(sW[t + 1], vb[(t + 1) * DD + lane], o1);
        o2 = fmaf(sW[t + 2], vb[(t + 2) * DD + lane], o2);
        o3 = fmaf(sW[t + 3], vb[(t + 3) * DD + lane], o3);
      } else {
        #pragma unroll
        for (int j = 0; j < 4; ++j) {
          int tj = t + j;
          if (tj < TT) o0 = fmaf(sW[tj], vb[tj * DD + lane], o0);
        }
      }
    }
    scratch[wid * 64 + lane] = (o0 + o1) + (o2 + o3);
  }
  __syncthreads();

  if (tid < DD)
    out[b * DD + tid] = (scratch[tid] + scratch[64 + tid])
                      + (scratch[128 + tid] + scratch[192 + tid]);
}

extern "C" void kernel_launch(void* const* d_in, const int* in_sizes, int n_in,
                              void* d_out, int out_size, void* d_ws, size_t ws_size,
                              hipStream_t stream) {
  const float* q    = (const float*)d_in[0];
  const float* k    = (const float*)d_in[1];
  const float* v    = (const float*)d_in[2];
  const int*   mask = (const int*)d_in[3];
  const float* W0   = (const float*)d_in[4];
  const float* b0   = (const float*)d_in[5];
  const float* W1   = (const float*)d_in[6];
  const float* b1   = (const float*)d_in[7];
  const float* Wf   = (const float*)d_in[8];
  float* out = (float*)d_out;
  din_attn<<<dim3(NB), dim3(256), 0, stream>>>(q, k, v, mask, W0, b0, W1, b1, Wf, out);
}